// Round 7
// baseline (99.817 us; speedup 1.0000x reference)
//
#include <hip/hip_runtime.h>
#include <hip/hip_bf16.h>

// Trittention, factorized:
//   z[q,h] = sum_{t<=q} Eqk[q,t]*v2[t,h]*G_q[t,h] / sum_{t<=q} Eqk[q,t]*g_q[t]
//   G_q[t,h] = sum_{s<=q} Ekk[s,t]*silu(v1)[s,h]   (prefix over s)
// R6: chunk partials fused into the score kernel (CS=32 == score s-tile),
// scan kernel deleted (attn2 sums <=5 chunk partials directly), projm at
// 32x32 tiles / 960 blocks, 2-deep register prefetch in projm & outm.

constexpr int Tn = 192;
constexpr int DM = 512;
constexpr int NH = 8;
constexpr int HD = 64;
constexpr int TT = Tn * Tn;
constexpr int NCc = 6;           // chunks of 32 s-rows
constexpr int CSc = 32;

typedef __bf16 bf16_t;
typedef bf16_t bf16x8 __attribute__((ext_vector_type(8)));
typedef bf16_t bf16x4 __attribute__((ext_vector_type(4)));
typedef float  f32x4  __attribute__((ext_vector_type(4)));

struct bf16pair { bf16_t h, l; };
__device__ __forceinline__ bf16pair split_bf16(float v) {
    bf16pair r;
    r.h = (bf16_t)v;
    r.l = (bf16_t)(v - (float)r.h);
    return r;
}

// ---------------- Kernel 0: convert x + transpose-convert weights ----------
__global__ __launch_bounds__(256) void k_convert(
    const float* __restrict__ x,    const float* __restrict__ Wkkq,
    const float* __restrict__ Wv1,  const float* __restrict__ Wv2,
    const float* __restrict__ Wout,
    bf16_t* __restrict__ xh,    bf16_t* __restrict__ xl,
    bf16_t* __restrict__ wkkqh, bf16_t* __restrict__ wkkql,
    bf16_t* __restrict__ wv1h,  bf16_t* __restrict__ wv1l,
    bf16_t* __restrict__ wv2h,  bf16_t* __restrict__ wv2l,
    bf16_t* __restrict__ wouth, bf16_t* __restrict__ woutl)
{
    const int bid = blockIdx.x;
    const int tid = threadIdx.x;

    if (bid >= 1536) {   // x path
        const int idx = (bid - 1536) * 1024 + tid * 4;
        const float4 v = *reinterpret_cast<const float4*>(&x[idx]);
        bf16x4 hv, lv;
        bf16pair p0 = split_bf16(v.x), p1 = split_bf16(v.y);
        bf16pair p2 = split_bf16(v.z), p3 = split_bf16(v.w);
        hv[0] = p0.h; lv[0] = p0.l; hv[1] = p1.h; lv[1] = p1.l;
        hv[2] = p2.h; lv[2] = p2.l; hv[3] = p3.h; lv[3] = p3.l;
        *reinterpret_cast<bf16x4*>(&xh[idx]) = hv;
        *reinterpret_cast<bf16x4*>(&xl[idx]) = lv;
        return;
    }

    const float* src; bf16_t* dh; bf16_t* dl; int N, lb;
    if (bid < 768)       { src = Wkkq; dh = wkkqh; dl = wkkql; N = 1536; lb = bid; }
    else if (bid < 1024) { src = Wv1;  dh = wv1h;  dl = wv1l;  N = 512;  lb = bid - 768; }
    else if (bid < 1280) { src = Wv2;  dh = wv2h;  dl = wv2l;  N = 512;  lb = bid - 1024; }
    else                 { src = Wout; dh = wouth; dl = woutl; N = 512;  lb = bid - 1280; }

    const int ntn = N >> 5;
    const int k0 = (lb / ntn) * 32, n0 = (lb % ntn) * 32;

    __shared__ float T[32][33];
    const int r = tid >> 3, c4 = (tid & 7) * 4;
    const float4 v = *reinterpret_cast<const float4*>(&src[(k0 + r) * N + n0 + c4]);
    T[r][c4] = v.x; T[r][c4 + 1] = v.y; T[r][c4 + 2] = v.z; T[r][c4 + 3] = v.w;
    __syncthreads();

    const int nr = tid >> 3, kc4 = (tid & 7) * 4;
    bf16x4 hv, lv;
#pragma unroll
    for (int i = 0; i < 4; ++i) {
        bf16pair p = split_bf16(T[kc4 + i][nr]);
        hv[i] = p.h; lv[i] = p.l;
    }
    *reinterpret_cast<bf16x4*>(&dh[(n0 + nr) * DM + k0 + kc4]) = hv;
    *reinterpret_cast<bf16x4*>(&dl[(n0 + nr) * DM + k0 + kc4]) = lv;
}

// ---------------- Kernel 1: MFMA projection GEMM ----------------
// [384x512] @ [512x2560]; 32x32 tile, 4 waves (16x16 quadrant each),
// 2-deep register prefetch.
__global__ __launch_bounds__(256) void k_projm(
    const bf16_t* __restrict__ xh,    const bf16_t* __restrict__ xl,
    const bf16_t* __restrict__ wkkqh, const bf16_t* __restrict__ wkkql,
    const bf16_t* __restrict__ wv1h,  const bf16_t* __restrict__ wv1l,
    const bf16_t* __restrict__ wv2h,  const bf16_t* __restrict__ wv2l,
    const float* __restrict__ bkkq, const float* __restrict__ bv1,
    const float* __restrict__ bv2,
    float* __restrict__ k1, float* __restrict__ k2, float* __restrict__ qv,
    float* __restrict__ sv1, float* __restrict__ v2o)
{
    const int bx = blockIdx.x, by = blockIdx.y;   // 80 col-tiles x 12 row-tiles
    const int tid = threadIdx.x;
    const int w = tid >> 6, lane = tid & 63;
    const int wm = w & 1, wn = w >> 1;            // quadrant: row half, col half
    const int lr = lane & 15, lk = (lane >> 4) * 8;

    const bf16_t *Bh, *Bl; int nbase;
    if (bx < 48)      { Bh = wkkqh; Bl = wkkql; nbase = bx * 32; }
    else if (bx < 64) { Bh = wv1h;  Bl = wv1l;  nbase = bx * 32 - 1536; }
    else              { Bh = wv2h;  Bl = wv2l;  nbase = bx * 32 - 2048; }

    const int arow = by * 32 + wm * 16 + lr;
    const int brow = nbase + wn * 16 + lr;

    f32x4 acc = {0.f,0.f,0.f,0.f};
    bf16x8 A_ah, A_al, A_bh, A_bl;
    bf16x8 B_ah, B_al, B_bh, B_bl;

#define PLD(P_, KS) do { const int ko_ = (KS) * 32 + lk;                     \
    P_##ah = *reinterpret_cast<const bf16x8*>(&xh[arow * DM + ko_]);         \
    P_##al = *reinterpret_cast<const bf16x8*>(&xl[arow * DM + ko_]);         \
    P_##bh = *reinterpret_cast<const bf16x8*>(&Bh[brow * DM + ko_]);         \
    P_##bl = *reinterpret_cast<const bf16x8*>(&Bl[brow * DM + ko_]); } while (0)
#define PMM(P_) do {                                                                    \
    acc = __builtin_amdgcn_mfma_f32_16x16x32_bf16(P_##ah, P_##bh, acc, 0, 0, 0);        \
    acc = __builtin_amdgcn_mfma_f32_16x16x32_bf16(P_##ah, P_##bl, acc, 0, 0, 0);        \
    acc = __builtin_amdgcn_mfma_f32_16x16x32_bf16(P_##al, P_##bh, acc, 0, 0, 0); } while (0)
#define PSTEP(P_, KN) do { PMM(P_); if ((KN) < 16) PLD(P_, KN); } while (0)

    PLD(A_, 0); PLD(B_, 1);
    PSTEP(A_, 2);  PSTEP(B_, 3);  PSTEP(A_, 4);  PSTEP(B_, 5);
    PSTEP(A_, 6);  PSTEP(B_, 7);  PSTEP(A_, 8);  PSTEP(B_, 9);
    PSTEP(A_, 10); PSTEP(B_, 11); PSTEP(A_, 12); PSTEP(B_, 13);
    PSTEP(A_, 14); PSTEP(B_, 15); PSTEP(A_, 16); PSTEP(B_, 17);
#undef PLD
#undef PMM
#undef PSTEP

    const int gcol = bx * 32 + wn * 16 + lr;
#pragma unroll
    for (int r = 0; r < 4; ++r) {
        const int row = by * 32 + wm * 16 + (lane >> 4) * 4 + r;
        const int b = row / Tn, t = row % Tn;
        const float a = acc[r];
        if (gcol < 1536) {
            const float val = a + bkkq[gcol];
            const int third = gcol >> 9, nh = gcol & 511, n = nh >> 6, hh = nh & 63;
            float* dst = (third == 0) ? k1 : (third == 1) ? k2 : qv;
            dst[((b * NH + n) * Tn + t) * HD + hh] = val;
        } else if (gcol < 2048) {
            const int c = gcol - 1536;
            float val = a + bv1[c];
            val = val / (1.f + __expf(-val));
            sv1[((b * NH + (c >> 6)) * Tn + t) * HD + (c & 63)] = val;
        } else {
            const int c = gcol - 2048;
            v2o[((b * NH + (c >> 6)) * Tn + t) * HD + (c & 63)] = a + bv2[c];
        }
    }
}

// ---------------- Kernel 2: exp tables + fused chunk partials ----------------
// bx<36: Ekk tile (st,tt) + P/gP partial for chunk c=st over its t-tile.
// bx>=36: Eqk tile only.
__global__ __launch_bounds__(256) void k_scoresP(
    const float* __restrict__ k1, const float* __restrict__ k2,
    const float* __restrict__ qv, const float* __restrict__ sv1,
    float* __restrict__ Ekk, float* __restrict__ Eqk,
    float* __restrict__ P, float* __restrict__ gP)
{
    const int bn = blockIdx.y;
    int bx = blockIdx.x;
    const int mat = (bx >= 36) ? 1 : 0;
    if (mat) bx -= 36;
    const int st = bx / 6, tt = bx % 6;
    const float* A  = ((mat == 0) ? k1 : qv) + bn * Tn * HD;
    const float* Bm = k2 + bn * Tn * HD;
    float* E = ((mat == 0) ? Ekk : Eqk) + bn * TT;

    __shared__ float As[32][65], Bs[32][65], Vs[32][65];
    __shared__ float Es[32][33];
    const int tid = threadIdx.x;
    for (int i = tid; i < 32 * 64; i += 256) {
        const int r = i >> 6, h = i & 63;
        As[r][h] = A[(st * 32 + r) * HD + h];
        Bs[r][h] = Bm[(tt * 32 + r) * HD + h];
        if (mat == 0) Vs[r][h] = sv1[bn * Tn * HD + (st * 32 + r) * HD + h];
    }
    __syncthreads();

    const int tx = tid & 15, ty = tid >> 4;
    const int r0 = ty * 2, c0 = tx * 2;
    float a00 = 0.f, a01 = 0.f, a10 = 0.f, a11 = 0.f;
#pragma unroll
    for (int h = 0; h < 64; ++h) {
        const float ar0 = As[r0][h], ar1 = As[r0 + 1][h];
        const float bc0 = Bs[c0][h], bc1 = Bs[c0 + 1][h];
        a00 = fmaf(ar0, bc0, a00); a01 = fmaf(ar0, bc1, a01);
        a10 = fmaf(ar1, bc0, a10); a11 = fmaf(ar1, bc1, a11);
    }
    constexpr float sc = 1.f / 64.f;
    const float e00 = __expf(a00 * sc), e01 = __expf(a01 * sc);
    const float e10 = __expf(a10 * sc), e11 = __expf(a11 * sc);
    const int gr = st * 32 + r0, gc = tt * 32 + c0;
    E[(gr)     * Tn + gc]     = e00;
    E[(gr)     * Tn + gc + 1] = e01;
    E[(gr + 1) * Tn + gc]     = e10;
    E[(gr + 1) * Tn + gc + 1] = e11;

    if (mat == 0) {
        Es[r0][c0] = e00; Es[r0][c0 + 1] = e01;
        Es[r0 + 1][c0] = e10; Es[r0 + 1][c0 + 1] = e11;
        __syncthreads();

        // P[bn][c=st][h][t-tile]: thread h = tid>>2, t offsets tp0..tp0+7
        const int h   = tid >> 2;
        const int tp0 = (tid & 3) * 8;
        float p[8] = {0.f,0.f,0.f,0.f,0.f,0.f,0.f,0.f};
        for (int s = 0; s < 32; ++s) {
            const float a = Vs[s][h];
#pragma unroll
            for (int j = 0; j < 8; ++j) p[j] = fmaf(Es[s][tp0 + j], a, p[j]);
        }
        float* pd = P + ((bn * NCc + st) * HD + h) * Tn + tt * 32 + tp0;
        *reinterpret_cast<float4*>(&pd[0]) = make_float4(p[0], p[1], p[2], p[3]);
        *reinterpret_cast<float4*>(&pd[4]) = make_float4(p[4], p[5], p[6], p[7]);

        if (tid < 32) {
            float s = 0.f;
#pragma unroll
            for (int ss = 0; ss < 32; ++ss) s += Es[ss][tid];
            gP[(bn * NCc + st) * Tn + tt * 32 + tid] = s;
        }
    }
}

// ---------------- Kernel 3: attention from unscanned chunk partials ---------
__global__ __launch_bounds__(256) void k_attn2(
    const float* __restrict__ Ekk, const float* __restrict__ Eqk,
    const float* __restrict__ sv1, const float* __restrict__ v2,
    const float* __restrict__ P,   const float* __restrict__ gP,
    float* __restrict__ z)
{
    const int hq = blockIdx.x;
    const int qt = blockIdx.y;
    const int bn = blockIdx.z;
    const int b = bn >> 3, n = bn & 7;
    const int tid = threadIdx.x;
    const int tg  = tid & 15;
    const int hh  = tid >> 4;
    const int h   = hq * 16 + hh;
    const int t0  = tg * 12;
    const int q0  = qt * 12;
    const int cb  = q0 >> 5;   // chunks fully below q0 (CSc=32)

    const float* ekk = Ekk + bn * TT;
    const float* eqk = Eqk + bn * TT;
    const float* s1  = sv1 + bn * Tn * HD;
    const float* vv  = v2  + bn * Tn * HD;

    float G[12], g[12];
#pragma unroll
    for (int j = 0; j < 12; ++j) { G[j] = 0.f; g[j] = 0.f; }

    for (int c = 0; c < cb; ++c) {
        const float* pb = P  + ((bn * NCc + c) * HD + h) * Tn + t0;
        const float* gb = gP + (bn * NCc + c) * Tn + t0;
#pragma unroll
        for (int jj = 0; jj < 3; ++jj) {
            const float4 pv = *reinterpret_cast<const float4*>(&pb[4 * jj]);
            G[4*jj+0] += pv.x; G[4*jj+1] += pv.y; G[4*jj+2] += pv.z; G[4*jj+3] += pv.w;
            const float4 gv = *reinterpret_cast<const float4*>(&gb[4 * jj]);
            g[4*jj+0] += gv.x; g[4*jj+1] += gv.y; g[4*jj+2] += gv.z; g[4*jj+3] += gv.w;
        }
    }

    float vvr[12];
#pragma unroll
    for (int j = 0; j < 12; ++j) vvr[j] = vv[(t0 + j) * HD + h];

    for (int s = CSc * cb; s < q0; ++s) {
        const float a = s1[s * HD + h];
        const float* ek = ekk + s * Tn + t0;
#pragma unroll
        for (int jj = 0; jj < 3; ++jj) {
            const float4 ev = *reinterpret_cast<const float4*>(&ek[4 * jj]);
            G[4*jj+0] = fmaf(ev.x, a, G[4*jj+0]); g[4*jj+0] += ev.x;
            G[4*jj+1] = fmaf(ev.y, a, G[4*jj+1]); g[4*jj+1] += ev.y;
            G[4*jj+2] = fmaf(ev.z, a, G[4*jj+2]); g[4*jj+2] += ev.z;
            G[4*jj+3] = fmaf(ev.w, a, G[4*jj+3]); g[4*jj+3] += ev.w;
        }
    }

    for (int q = q0; q < q0 + 12; ++q) {
        {
            const float a = s1[q * HD + h];
            const float* ek = ekk + q * Tn + t0;
#pragma unroll
            for (int jj = 0; jj < 3; ++jj) {
                const float4 ev = *reinterpret_cast<const float4*>(&ek[4 * jj]);
                G[4*jj+0] = fmaf(ev.x, a, G[4*jj+0]); g[4*jj+0] += ev.x;
                G[4*jj+1] = fmaf(ev.y, a, G[4*jj+1]); g[4*jj+1] += ev.y;
                G[4*jj+2] = fmaf(ev.z, a, G[4*jj+2]); g[4*jj+2] += ev.z;
                G[4*jj+3] = fmaf(ev.w, a, G[4*jj+3]); g[4*jj+3] += ev.w;
            }
        }
        const float* eq = eqk + q * Tn + t0;
        float zp = 0.f, Zp = 0.f;
#pragma unroll
        for (int jj = 0; jj < 3; ++jj) {
            const float4 ev = *reinterpret_cast<const float4*>(&eq[4 * jj]);
            const float e0 = (t0 + 4*jj + 0 <= q) ? ev.x : 0.f;
            const float e1 = (t0 + 4*jj + 1 <= q) ? ev.y : 0.f;
            const float e2 = (t0 + 4*jj + 2 <= q) ? ev.z : 0.f;
            const float e3 = (t0 + 4*jj + 3 <= q) ? ev.w : 0.f;
            zp = fmaf(e0 * vvr[4*jj+0], G[4*jj+0], zp); Zp = fmaf(e0, g[4*jj+0], Zp);
            zp = fmaf(e1 * vvr[4*jj+1], G[4*jj+1], zp); Zp = fmaf(e1, g[4*jj+1], Zp);
            zp = fmaf(e2 * vvr[4*jj+2], G[4*jj+2], zp); Zp = fmaf(e2, g[4*jj+2], Zp);
            zp = fmaf(e3 * vvr[4*jj+3], G[4*jj+3], zp); Zp = fmaf(e3, g[4*jj+3], Zp);
        }
        zp += __shfl_xor(zp, 1); zp += __shfl_xor(zp, 2);
        zp += __shfl_xor(zp, 4); zp += __shfl_xor(zp, 8);
        Zp += __shfl_xor(Zp, 1); Zp += __shfl_xor(Zp, 2);
        Zp += __shfl_xor(Zp, 4); Zp += __shfl_xor(Zp, 8);
        if (tg == 0) z[((b * Tn + q) * NH + n) * HD + h] = zp / Zp;
    }
}

// ---------------- Kernel 4: MFMA output projection ----------------
// [384x512] @ [512x512]; 16x64 tile, 4 waves (16x16 each), 2-deep prefetch,
// A (z) split fp32->bf16 hi/lo in-register.
__global__ __launch_bounds__(256) void k_outm(
    const float* __restrict__ z,
    const bf16_t* __restrict__ wouth, const bf16_t* __restrict__ woutl,
    const float* __restrict__ bout, float* __restrict__ out)
{
    const int bx = blockIdx.x, by = blockIdx.y;   // 8 col-tiles, 24 row-tiles
    const int tid = threadIdx.x;
    const int w = tid >> 6, lane = tid & 63;
    const int lr = lane & 15, lk = (lane >> 4) * 8;
    const int arow = by * 16 + lr;
    const int brow = bx * 64 + w * 16 + lr;

    f32x4 acc = {0.f,0.f,0.f,0.f};
    bf16x8 A_ah, A_al, A_bh, A_bl;
    bf16x8 B_ah, B_al, B_bh, B_bl;

#define OLD(P_, KS) do { const int ko_ = (KS) * 32 + lk;                         \
    const float4 u0 = *reinterpret_cast<const float4*>(&z[arow * DM + ko_]);     \
    const float4 u1 = *reinterpret_cast<const float4*>(&z[arow * DM + ko_ + 4]); \
    bf16pair q0 = split_bf16(u0.x), q1 = split_bf16(u0.y);                       \
    bf16pair q2 = split_bf16(u0.z), q3 = split_bf16(u0.w);                       \
    bf16pair q4 = split_bf16(u1.x), q5 = split_bf16(u1.y);                       \
    bf16pair q6 = split_bf16(u1.z), q7 = split_bf16(u1.w);                       \
    P_##ah[0] = q0.h; P_##al[0] = q0.l; P_##ah[1] = q1.h; P_##al[1] = q1.l;      \
    P_##ah[2] = q2.h; P_##al[2] = q2.l; P_##ah[3] = q3.h; P_##al[3] = q3.l;      \
    P_##ah[4] = q4.h; P_##al[4] = q4.l; P_##ah[5] = q5.h; P_##al[5] = q5.l;      \
    P_##ah[6] = q6.h; P_##al[6] = q6.l; P_##ah[7] = q7.h; P_##al[7] = q7.l;      \
    P_##bh = *reinterpret_cast<const bf16x8*>(&wouth[brow * DM + ko_]);          \
    P_##bl = *reinterpret_cast<const bf16x8*>(&woutl[brow * DM + ko_]); } while (0)
#define OMM(P_) do {                                                                   \
    acc = __builtin_amdgcn_mfma_f32_16x16x32_bf16(P_##ah, P_##bh, acc, 0, 0, 0);       \
    acc = __builtin_amdgcn_mfma_f32_16x16x32_bf16(P_##ah, P_##bl, acc, 0, 0, 0);       \
    acc = __builtin_amdgcn_mfma_f32_16x16x32_bf16(P_##al, P_##bh, acc, 0, 0, 0); } while (0)
#define OSTEP(P_, KN) do { OMM(P_); if ((KN) < 16) OLD(P_, KN); } while (0)

    OLD(A_, 0); OLD(B_, 1);
    OSTEP(A_, 2);  OSTEP(B_, 3);  OSTEP(A_, 4);  OSTEP(B_, 5);
    OSTEP(A_, 6);  OSTEP(B_, 7);  OSTEP(A_, 8);  OSTEP(B_, 9);
    OSTEP(A_, 10); OSTEP(B_, 11); OSTEP(A_, 12); OSTEP(B_, 13);
    OSTEP(A_, 14); OSTEP(B_, 15); OSTEP(A_, 16); OSTEP(B_, 17);
#undef OLD
#undef OMM
#undef OSTEP

    const int col = bx * 64 + w * 16 + lr;
#pragma unroll
    for (int r = 0; r < 4; ++r) {
        const int row = by * 16 + (lane >> 4) * 4 + r;
        out[row * DM + col] = acc[r] + bout[col];
    }
}

extern "C" void kernel_launch(void* const* d_in, const int* in_sizes, int n_in,
                              void* d_out, int out_size, void* d_ws, size_t ws_size,
                              hipStream_t stream) {
    const float* x    = (const float*)d_in[0];
    const float* Wkkq = (const float*)d_in[1];
    const float* bkkq = (const float*)d_in[2];
    const float* Wv1  = (const float*)d_in[3];
    const float* bv1  = (const float*)d_in[4];
    const float* Wv2  = (const float*)d_in[5];
    const float* bv2  = (const float*)d_in[6];
    const float* Wout = (const float*)d_in[7];
    const float* bout = (const float*)d_in[8];
    float* out = (float*)d_out;

    // float region
    float* ws  = (float*)d_ws;
    float* k1  = ws;
    float* k2  = k1  + 196608;
    float* qv  = k2  + 196608;
    float* sv1 = qv  + 196608;
    float* v2  = sv1 + 196608;
    float* z   = v2  + 196608;
    float* Ekk = z   + 196608;
    float* Eqk = Ekk + 589824;
    float* P   = Eqk + 589824;           // 16*6*64*192 = 1179648
    float* gP  = P   + 1179648;          // 16*6*192 = 18432
    // bf16 region
    bf16_t* bws   = (bf16_t*)(gP + 18432);
    bf16_t* xh    = bws;
    bf16_t* xl    = xh    + 196608;
    bf16_t* wkkqh = xl    + 196608;
    bf16_t* wkkql = wkkqh + 786432;
    bf16_t* wv1h  = wkkql + 786432;
    bf16_t* wv1l  = wv1h  + 262144;
    bf16_t* wv2h  = wv1l  + 262144;
    bf16_t* wv2l  = wv2h  + 262144;
    bf16_t* wouth = wv2l  + 262144;
    bf16_t* woutl = wouth + 262144;

    k_convert<<<dim3(1728),      256, 0, stream>>>(x, Wkkq, Wv1, Wv2, Wout,
                                                   xh, xl, wkkqh, wkkql,
                                                   wv1h, wv1l, wv2h, wv2l, wouth, woutl);
    k_projm  <<<dim3(80, 12),    256, 0, stream>>>(xh, xl, wkkqh, wkkql, wv1h, wv1l,
                                                   wv2h, wv2l, bkkq, bv1, bv2,
                                                   k1, k2, qv, sv1, v2);
    k_scoresP<<<dim3(72, 16),    256, 0, stream>>>(k1, k2, qv, sv1, Ekk, Eqk, P, gP);
    k_attn2  <<<dim3(4, 16, 16), 256, 0, stream>>>(Ekk, Eqk, sv1, v2, P, gP, z);
    k_outm   <<<dim3(8, 24),     256, 0, stream>>>(z, wouth, woutl, bout, out);
}

// Round 8
// 83.938 us; speedup vs baseline: 1.1892x; 1.1892x over previous
//
#include <hip/hip_runtime.h>
#include <hip/hip_bf16.h>

// Trittention, factorized:
//   z[q,h] = sum_{t<=q} Eqk[q,t]*v2[t,h]*G_q[t,h] / sum_{t<=q} Eqk[q,t]*g_q[t]
//   G_q[t,h] = sum_{s<=q} Ekk[s,t]*silu(v1)[s,h]   (prefix over s)
// R7: k_convert deleted. Both MFMA kernels read fp32 directly and split to
// bf16 hi/lo in-register (A.B ~ Ah.Bh + Ah.Bl + Al.Bh, fp32 accum).
// Pipeline: projm -> scoresP -> attn2 -> outm (4 graph nodes).

constexpr int Tn = 192;
constexpr int DM = 512;
constexpr int NH = 8;
constexpr int HD = 64;
constexpr int TT = Tn * Tn;
constexpr int NCc = 6;           // chunks of 32 s-rows
constexpr int CSc = 32;

typedef __bf16 bf16_t;
typedef bf16_t bf16x8 __attribute__((ext_vector_type(8)));
typedef float  f32x4  __attribute__((ext_vector_type(4)));

struct bf16pair { bf16_t h, l; };
__device__ __forceinline__ bf16pair split_bf16(float v) {
    bf16pair r;
    r.h = (bf16_t)v;
    r.l = (bf16_t)(v - (float)r.h);
    return r;
}

// ---------------- Kernel 1: MFMA projection GEMM (fp32 in, in-reg split) ----
// [384x512] @ [512x2560]; 32x32 tile, 4 waves (16x16 quadrant each),
// 2-deep register prefetch. W read as 8 stride-ldw dwords (coalesced per
// 16-lane group), x read as 2x float4.
__global__ __launch_bounds__(256) void k_projm(
    const float* __restrict__ x,
    const float* __restrict__ Wkkq, const float* __restrict__ Wv1,
    const float* __restrict__ Wv2,
    const float* __restrict__ bkkq, const float* __restrict__ bv1,
    const float* __restrict__ bv2,
    float* __restrict__ k1, float* __restrict__ k2, float* __restrict__ qv,
    float* __restrict__ sv1, float* __restrict__ v2o)
{
    const int bx = blockIdx.x, by = blockIdx.y;   // 80 col-tiles x 12 row-tiles
    const int tid = threadIdx.x;
    const int w = tid >> 6, lane = tid & 63;
    const int wm = w & 1, wn = w >> 1;
    const int lr = lane & 15, lk = (lane >> 4) * 8;

    const float* Wp; int ldw, cloc;
    if (bx < 48)      { Wp = Wkkq; ldw = 1536; cloc = bx * 32; }
    else if (bx < 64) { Wp = Wv1;  ldw = 512;  cloc = bx * 32 - 1536; }
    else              { Wp = Wv2;  ldw = 512;  cloc = bx * 32 - 2048; }

    const int arow = by * 32 + wm * 16 + lr;
    const int bcol = cloc + wn * 16 + lr;
    const float* xrow = x + arow * DM;

    f32x4 acc = {0.f,0.f,0.f,0.f};
    bf16x8 A_ah, A_al, A_bh, A_bl;
    bf16x8 B_ah, B_al, B_bh, B_bl;

#define PLD(P_, KS) do { const int ko_ = (KS) * 32 + lk;                                  \
    const float4 u0 = *reinterpret_cast<const float4*>(&xrow[ko_]);                       \
    const float4 u1 = *reinterpret_cast<const float4*>(&xrow[ko_ + 4]);                   \
    const float* wp_ = Wp + ko_ * ldw + bcol;                                             \
    const float w0_ = wp_[0],       w1_ = wp_[ldw],     w2_ = wp_[2 * ldw];               \
    const float w3_ = wp_[3 * ldw], w4_ = wp_[4 * ldw], w5_ = wp_[5 * ldw];               \
    const float w6_ = wp_[6 * ldw], w7_ = wp_[7 * ldw];                                   \
    bf16pair t0_ = split_bf16(u0.x), t1_ = split_bf16(u0.y);                              \
    bf16pair t2_ = split_bf16(u0.z), t3_ = split_bf16(u0.w);                              \
    bf16pair t4_ = split_bf16(u1.x), t5_ = split_bf16(u1.y);                              \
    bf16pair t6_ = split_bf16(u1.z), t7_ = split_bf16(u1.w);                              \
    P_##ah[0] = t0_.h; P_##al[0] = t0_.l; P_##ah[1] = t1_.h; P_##al[1] = t1_.l;           \
    P_##ah[2] = t2_.h; P_##al[2] = t2_.l; P_##ah[3] = t3_.h; P_##al[3] = t3_.l;           \
    P_##ah[4] = t4_.h; P_##al[4] = t4_.l; P_##ah[5] = t5_.h; P_##al[5] = t5_.l;           \
    P_##ah[6] = t6_.h; P_##al[6] = t6_.l; P_##ah[7] = t7_.h; P_##al[7] = t7_.l;           \
    bf16pair s0_ = split_bf16(w0_), s1_ = split_bf16(w1_);                                \
    bf16pair s2_ = split_bf16(w2_), s3_ = split_bf16(w3_);                                \
    bf16pair s4_ = split_bf16(w4_), s5_ = split_bf16(w5_);                                \
    bf16pair s6_ = split_bf16(w6_), s7_ = split_bf16(w7_);                                \
    P_##bh[0] = s0_.h; P_##bl[0] = s0_.l; P_##bh[1] = s1_.h; P_##bl[1] = s1_.l;           \
    P_##bh[2] = s2_.h; P_##bl[2] = s2_.l; P_##bh[3] = s3_.h; P_##bl[3] = s3_.l;           \
    P_##bh[4] = s4_.h; P_##bl[4] = s4_.l; P_##bh[5] = s5_.h; P_##bl[5] = s5_.l;           \
    P_##bh[6] = s6_.h; P_##bl[6] = s6_.l; P_##bh[7] = s7_.h; P_##bl[7] = s7_.l; } while (0)
#define PMM(P_) do {                                                                    \
    acc = __builtin_amdgcn_mfma_f32_16x16x32_bf16(P_##ah, P_##bh, acc, 0, 0, 0);        \
    acc = __builtin_amdgcn_mfma_f32_16x16x32_bf16(P_##ah, P_##bl, acc, 0, 0, 0);        \
    acc = __builtin_amdgcn_mfma_f32_16x16x32_bf16(P_##al, P_##bh, acc, 0, 0, 0); } while (0)
#define PSTEP(P_, KN) do { PMM(P_); if ((KN) < 16) PLD(P_, KN); } while (0)

    PLD(A_, 0); PLD(B_, 1);
    PSTEP(A_, 2);  PSTEP(B_, 3);  PSTEP(A_, 4);  PSTEP(B_, 5);
    PSTEP(A_, 6);  PSTEP(B_, 7);  PSTEP(A_, 8);  PSTEP(B_, 9);
    PSTEP(A_, 10); PSTEP(B_, 11); PSTEP(A_, 12); PSTEP(B_, 13);
    PSTEP(A_, 14); PSTEP(B_, 15); PSTEP(A_, 16); PSTEP(B_, 17);
#undef PLD
#undef PMM
#undef PSTEP

    const int gcol = bx * 32 + wn * 16 + lr;
#pragma unroll
    for (int r = 0; r < 4; ++r) {
        const int row = by * 32 + wm * 16 + (lane >> 4) * 4 + r;
        const int b = row / Tn, t = row % Tn;
        const float a = acc[r];
        if (gcol < 1536) {
            const float val = a + bkkq[gcol];
            const int third = gcol >> 9, nh = gcol & 511, n = nh >> 6, hh = nh & 63;
            float* dst = (third == 0) ? k1 : (third == 1) ? k2 : qv;
            dst[((b * NH + n) * Tn + t) * HD + hh] = val;
        } else if (gcol < 2048) {
            const int c = gcol - 1536;
            float val = a + bv1[c];
            val = val / (1.f + __expf(-val));
            sv1[((b * NH + (c >> 6)) * Tn + t) * HD + (c & 63)] = val;
        } else {
            const int c = gcol - 2048;
            v2o[((b * NH + (c >> 6)) * Tn + t) * HD + (c & 63)] = a + bv2[c];
        }
    }
}

// ---------------- Kernel 2: exp tables + fused chunk partials ----------------
__global__ __launch_bounds__(256) void k_scoresP(
    const float* __restrict__ k1, const float* __restrict__ k2,
    const float* __restrict__ qv, const float* __restrict__ sv1,
    float* __restrict__ Ekk, float* __restrict__ Eqk,
    float* __restrict__ P, float* __restrict__ gP)
{
    const int bn = blockIdx.y;
    int bx = blockIdx.x;
    const int mat = (bx >= 36) ? 1 : 0;
    if (mat) bx -= 36;
    const int st = bx / 6, tt = bx % 6;
    const float* A  = ((mat == 0) ? k1 : qv) + bn * Tn * HD;
    const float* Bm = k2 + bn * Tn * HD;
    float* E = ((mat == 0) ? Ekk : Eqk) + bn * TT;

    __shared__ float As[32][65], Bs[32][65], Vs[32][65];
    __shared__ float Es[32][33];
    const int tid = threadIdx.x;
    for (int i = tid; i < 32 * 64; i += 256) {
        const int r = i >> 6, h = i & 63;
        As[r][h] = A[(st * 32 + r) * HD + h];
        Bs[r][h] = Bm[(tt * 32 + r) * HD + h];
        if (mat == 0) Vs[r][h] = sv1[bn * Tn * HD + (st * 32 + r) * HD + h];
    }
    __syncthreads();

    const int tx = tid & 15, ty = tid >> 4;
    const int r0 = ty * 2, c0 = tx * 2;
    float a00 = 0.f, a01 = 0.f, a10 = 0.f, a11 = 0.f;
#pragma unroll
    for (int h = 0; h < 64; ++h) {
        const float ar0 = As[r0][h], ar1 = As[r0 + 1][h];
        const float bc0 = Bs[c0][h], bc1 = Bs[c0 + 1][h];
        a00 = fmaf(ar0, bc0, a00); a01 = fmaf(ar0, bc1, a01);
        a10 = fmaf(ar1, bc0, a10); a11 = fmaf(ar1, bc1, a11);
    }
    constexpr float sc = 1.f / 64.f;
    const float e00 = __expf(a00 * sc), e01 = __expf(a01 * sc);
    const float e10 = __expf(a10 * sc), e11 = __expf(a11 * sc);
    const int gr = st * 32 + r0, gc = tt * 32 + c0;
    E[(gr)     * Tn + gc]     = e00;
    E[(gr)     * Tn + gc + 1] = e01;
    E[(gr + 1) * Tn + gc]     = e10;
    E[(gr + 1) * Tn + gc + 1] = e11;

    if (mat == 0) {
        Es[r0][c0] = e00; Es[r0][c0 + 1] = e01;
        Es[r0 + 1][c0] = e10; Es[r0 + 1][c0 + 1] = e11;
        __syncthreads();

        const int h   = tid >> 2;
        const int tp0 = (tid & 3) * 8;
        float p[8] = {0.f,0.f,0.f,0.f,0.f,0.f,0.f,0.f};
        for (int s = 0; s < 32; ++s) {
            const float a = Vs[s][h];
#pragma unroll
            for (int j = 0; j < 8; ++j) p[j] = fmaf(Es[s][tp0 + j], a, p[j]);
        }
        float* pd = P + ((bn * NCc + st) * HD + h) * Tn + tt * 32 + tp0;
        *reinterpret_cast<float4*>(&pd[0]) = make_float4(p[0], p[1], p[2], p[3]);
        *reinterpret_cast<float4*>(&pd[4]) = make_float4(p[4], p[5], p[6], p[7]);

        if (tid < 32) {
            float s = 0.f;
#pragma unroll
            for (int ss = 0; ss < 32; ++ss) s += Es[ss][tid];
            gP[(bn * NCc + st) * Tn + tt * 32 + tid] = s;
        }
    }
}

// ---------------- Kernel 3: attention from unscanned chunk partials ---------
__global__ __launch_bounds__(256) void k_attn2(
    const float* __restrict__ Ekk, const float* __restrict__ Eqk,
    const float* __restrict__ sv1, const float* __restrict__ v2,
    const float* __restrict__ P,   const float* __restrict__ gP,
    float* __restrict__ z)
{
    const int hq = blockIdx.x;
    const int qt = blockIdx.y;
    const int bn = blockIdx.z;
    const int b = bn >> 3, n = bn & 7;
    const int tid = threadIdx.x;
    const int tg  = tid & 15;
    const int hh  = tid >> 4;
    const int h   = hq * 16 + hh;
    const int t0  = tg * 12;
    const int q0  = qt * 12;
    const int cb  = q0 >> 5;

    const float* ekk = Ekk + bn * TT;
    const float* eqk = Eqk + bn * TT;
    const float* s1  = sv1 + bn * Tn * HD;
    const float* vv  = v2  + bn * Tn * HD;

    float G[12], g[12];
#pragma unroll
    for (int j = 0; j < 12; ++j) { G[j] = 0.f; g[j] = 0.f; }

    for (int c = 0; c < cb; ++c) {
        const float* pb = P  + ((bn * NCc + c) * HD + h) * Tn + t0;
        const float* gb = gP + (bn * NCc + c) * Tn + t0;
#pragma unroll
        for (int jj = 0; jj < 3; ++jj) {
            const float4 pv = *reinterpret_cast<const float4*>(&pb[4 * jj]);
            G[4*jj+0] += pv.x; G[4*jj+1] += pv.y; G[4*jj+2] += pv.z; G[4*jj+3] += pv.w;
            const float4 gv = *reinterpret_cast<const float4*>(&gb[4 * jj]);
            g[4*jj+0] += gv.x; g[4*jj+1] += gv.y; g[4*jj+2] += gv.z; g[4*jj+3] += gv.w;
        }
    }

    float vvr[12];
#pragma unroll
    for (int j = 0; j < 12; ++j) vvr[j] = vv[(t0 + j) * HD + h];

    for (int s = CSc * cb; s < q0; ++s) {
        const float a = s1[s * HD + h];
        const float* ek = ekk + s * Tn + t0;
#pragma unroll
        for (int jj = 0; jj < 3; ++jj) {
            const float4 ev = *reinterpret_cast<const float4*>(&ek[4 * jj]);
            G[4*jj+0] = fmaf(ev.x, a, G[4*jj+0]); g[4*jj+0] += ev.x;
            G[4*jj+1] = fmaf(ev.y, a, G[4*jj+1]); g[4*jj+1] += ev.y;
            G[4*jj+2] = fmaf(ev.z, a, G[4*jj+2]); g[4*jj+2] += ev.z;
            G[4*jj+3] = fmaf(ev.w, a, G[4*jj+3]); g[4*jj+3] += ev.w;
        }
    }

    for (int q = q0; q < q0 + 12; ++q) {
        {
            const float a = s1[q * HD + h];
            const float* ek = ekk + q * Tn + t0;
#pragma unroll
            for (int jj = 0; jj < 3; ++jj) {
                const float4 ev = *reinterpret_cast<const float4*>(&ek[4 * jj]);
                G[4*jj+0] = fmaf(ev.x, a, G[4*jj+0]); g[4*jj+0] += ev.x;
                G[4*jj+1] = fmaf(ev.y, a, G[4*jj+1]); g[4*jj+1] += ev.y;
                G[4*jj+2] = fmaf(ev.z, a, G[4*jj+2]); g[4*jj+2] += ev.z;
                G[4*jj+3] = fmaf(ev.w, a, G[4*jj+3]); g[4*jj+3] += ev.w;
            }
        }
        const float* eq = eqk + q * Tn + t0;
        float zp = 0.f, Zp = 0.f;
#pragma unroll
        for (int jj = 0; jj < 3; ++jj) {
            const float4 ev = *reinterpret_cast<const float4*>(&eq[4 * jj]);
            const float e0 = (t0 + 4*jj + 0 <= q) ? ev.x : 0.f;
            const float e1 = (t0 + 4*jj + 1 <= q) ? ev.y : 0.f;
            const float e2 = (t0 + 4*jj + 2 <= q) ? ev.z : 0.f;
            const float e3 = (t0 + 4*jj + 3 <= q) ? ev.w : 0.f;
            zp = fmaf(e0 * vvr[4*jj+0], G[4*jj+0], zp); Zp = fmaf(e0, g[4*jj+0], Zp);
            zp = fmaf(e1 * vvr[4*jj+1], G[4*jj+1], zp); Zp = fmaf(e1, g[4*jj+1], Zp);
            zp = fmaf(e2 * vvr[4*jj+2], G[4*jj+2], zp); Zp = fmaf(e2, g[4*jj+2], Zp);
            zp = fmaf(e3 * vvr[4*jj+3], G[4*jj+3], zp); Zp = fmaf(e3, g[4*jj+3], Zp);
        }
        zp += __shfl_xor(zp, 1); zp += __shfl_xor(zp, 2);
        zp += __shfl_xor(zp, 4); zp += __shfl_xor(zp, 8);
        Zp += __shfl_xor(Zp, 1); Zp += __shfl_xor(Zp, 2);
        Zp += __shfl_xor(Zp, 4); Zp += __shfl_xor(Zp, 8);
        if (tg == 0) z[((b * Tn + q) * NH + n) * HD + h] = zp / Zp;
    }
}

// ---------------- Kernel 4: MFMA output projection (fp32 in, in-reg split) --
// [384x512] @ [512x512]; 16x64 tile, 4 waves (16x16 each), 2-deep prefetch.
__global__ __launch_bounds__(256) void k_outm(
    const float* __restrict__ z, const float* __restrict__ Wout,
    const float* __restrict__ bout, float* __restrict__ out)
{
    const int bx = blockIdx.x, by = blockIdx.y;   // 8 col-tiles, 24 row-tiles
    const int tid = threadIdx.x;
    const int w = tid >> 6, lane = tid & 63;
    const int lr = lane & 15, lk = (lane >> 4) * 8;
    const int arow = by * 16 + lr;
    const int bcol = bx * 64 + w * 16 + lr;
    const float* zrow = z + arow * DM;

    f32x4 acc = {0.f,0.f,0.f,0.f};
    bf16x8 A_ah, A_al, A_bh, A_bl;
    bf16x8 B_ah, B_al, B_bh, B_bl;

#define OLD(P_, KS) do { const int ko_ = (KS) * 32 + lk;                                  \
    const float4 u0 = *reinterpret_cast<const float4*>(&zrow[ko_]);                       \
    const float4 u1 = *reinterpret_cast<const float4*>(&zrow[ko_ + 4]);                   \
    const float* wp_ = Wout + ko_ * DM + bcol;                                            \
    const float w0_ = wp_[0],      w1_ = wp_[DM],     w2_ = wp_[2 * DM];                  \
    const float w3_ = wp_[3 * DM], w4_ = wp_[4 * DM], w5_ = wp_[5 * DM];                  \
    const float w6_ = wp_[6 * DM], w7_ = wp_[7 * DM];                                     \
    bf16pair t0_ = split_bf16(u0.x), t1_ = split_bf16(u0.y);                              \
    bf16pair t2_ = split_bf16(u0.z), t3_ = split_bf16(u0.w);                              \
    bf16pair t4_ = split_bf16(u1.x), t5_ = split_bf16(u1.y);                              \
    bf16pair t6_ = split_bf16(u1.z), t7_ = split_bf16(u1.w);                              \
    P_##ah[0] = t0_.h; P_##al[0] = t0_.l; P_##ah[1] = t1_.h; P_##al[1] = t1_.l;           \
    P_##ah[2] = t2_.h; P_##al[2] = t2_.l; P_##ah[3] = t3_.h; P_##al[3] = t3_.l;           \
    P_##ah[4] = t4_.h; P_##al[4] = t4_.l; P_##ah[5] = t5_.h; P_##al[5] = t5_.l;           \
    P_##ah[6] = t6_.h; P_##al[6] = t6_.l; P_##ah[7] = t7_.h; P_##al[7] = t7_.l;           \
    bf16pair s0_ = split_bf16(w0_), s1_ = split_bf16(w1_);                                \
    bf16pair s2_ = split_bf16(w2_), s3_ = split_bf16(w3_);                                \
    bf16pair s4_ = split_bf16(w4_), s5_ = split_bf16(w5_);                                \
    bf16pair s6_ = split_bf16(w6_), s7_ = split_bf16(w7_);                                \
    P_##bh[0] = s0_.h; P_##bl[0] = s0_.l; P_##bh[1] = s1_.h; P_##bl[1] = s1_.l;           \
    P_##bh[2] = s2_.h; P_##bl[2] = s2_.l; P_##bh[3] = s3_.h; P_##bl[3] = s3_.l;           \
    P_##bh[4] = s4_.h; P_##bl[4] = s4_.l; P_##bh[5] = s5_.h; P_##bl[5] = s5_.l;           \
    P_##bh[6] = s6_.h; P_##bl[6] = s6_.l; P_##bh[7] = s7_.h; P_##bl[7] = s7_.l; } while (0)
#define OMM(P_) do {                                                                   \
    acc = __builtin_amdgcn_mfma_f32_16x16x32_bf16(P_##ah, P_##bh, acc, 0, 0, 0);       \
    acc = __builtin_amdgcn_mfma_f32_16x16x32_bf16(P_##ah, P_##bl, acc, 0, 0, 0);       \
    acc = __builtin_amdgcn_mfma_f32_16x16x32_bf16(P_##al, P_##bh, acc, 0, 0, 0); } while (0)
#define OSTEP(P_, KN) do { OMM(P_); if ((KN) < 16) OLD(P_, KN); } while (0)

    OLD(A_, 0); OLD(B_, 1);
    OSTEP(A_, 2);  OSTEP(B_, 3);  OSTEP(A_, 4);  OSTEP(B_, 5);
    OSTEP(A_, 6);  OSTEP(B_, 7);  OSTEP(A_, 8);  OSTEP(B_, 9);
    OSTEP(A_, 10); OSTEP(B_, 11); OSTEP(A_, 12); OSTEP(B_, 13);
    OSTEP(A_, 14); OSTEP(B_, 15); OSTEP(A_, 16); OSTEP(B_, 17);
#undef OLD
#undef OMM
#undef OSTEP

#pragma unroll
    for (int r = 0; r < 4; ++r) {
        const int row = by * 16 + (lane >> 4) * 4 + r;
        out[row * DM + bcol] = acc[r] + bout[bcol];
    }
}

extern "C" void kernel_launch(void* const* d_in, const int* in_sizes, int n_in,
                              void* d_out, int out_size, void* d_ws, size_t ws_size,
                              hipStream_t stream) {
    const float* x    = (const float*)d_in[0];
    const float* Wkkq = (const float*)d_in[1];
    const float* bkkq = (const float*)d_in[2];
    const float* Wv1  = (const float*)d_in[3];
    const float* bv1  = (const float*)d_in[4];
    const float* Wv2  = (const float*)d_in[5];
    const float* bv2  = (const float*)d_in[6];
    const float* Wout = (const float*)d_in[7];
    const float* bout = (const float*)d_in[8];
    float* out = (float*)d_out;

    float* ws  = (float*)d_ws;
    float* k1  = ws;
    float* k2  = k1  + 196608;
    float* qv  = k2  + 196608;
    float* sv1 = qv  + 196608;
    float* v2  = sv1 + 196608;
    float* z   = v2  + 196608;
    float* Ekk = z   + 196608;
    float* Eqk = Ekk + 589824;
    float* P   = Eqk + 589824;           // 16*6*64*192
    float* gP  = P   + 1179648;          // 16*6*192

    k_projm  <<<dim3(80, 12),    256, 0, stream>>>(x, Wkkq, Wv1, Wv2,
                                                   bkkq, bv1, bv2,
                                                   k1, k2, qv, sv1, v2);
    k_scoresP<<<dim3(72, 16),    256, 0, stream>>>(k1, k2, qv, sv1, Ekk, Eqk, P, gP);
    k_attn2  <<<dim3(4, 16, 16), 256, 0, stream>>>(Ekk, Eqk, sv1, v2, P, gP, z);
    k_outm   <<<dim3(8, 24),     256, 0, stream>>>(z, Wout, bout, out);
}